// Round 1
// baseline (748.213 us; speedup 1.0000x reference)
//
#include <hip/hip_runtime.h>
#include <hip/hip_bf16.h>
#include <math.h>

#define BB 64
#define NN 256
#define DD 768
#define GG 300
#define KK 10
#define NEGV -9e15f

typedef __attribute__((ext_vector_type(8)))  short short8;
typedef __attribute__((ext_vector_type(4)))  short short4v;
typedef __attribute__((ext_vector_type(16))) float f32x16;

static __device__ __forceinline__ short f2bf(float f){
  __hip_bfloat16 b = __float2bfloat16(f);
  return __builtin_bit_cast(short, b);
}
static __device__ __forceinline__ float bf2f(short s){
  return __bfloat162float(__builtin_bit_cast(__hip_bfloat16, s));
}

// async global->LDS DMA, 16B per lane; dst is wave-uniform base (+lane*16 by HW)
static __device__ __forceinline__ void dma16(const void* g, void* l){
  __builtin_amdgcn_global_load_lds((const __attribute__((address_space(1))) void*)g,
                                   (__attribute__((address_space(3))) void*)l, 16, 0, 0);
}

__device__ __forceinline__ float blkReduceSum(float v, float* s){
  for(int o=32;o>0;o>>=1) v += __shfl_down(v,o,64);
  int nw = blockDim.x>>6;
  __syncthreads();
  if((threadIdx.x&63)==0) s[threadIdx.x>>6]=v;
  __syncthreads();
  float r=s[0];
  for(int i=1;i<nw;i++) r+=s[i];
  return r;
}

// ---------------------------------------------------------------------------
// Semantic prep A: arep[b][d] = masked mean of h over nodes. grid (64,3).
// ---------------------------------------------------------------------------
__global__ __launch_bounds__(256) void k_arep(const float* __restrict__ h,
    const float* __restrict__ amask, float* __restrict__ arep){
  int b = blockIdx.x, tid = threadIdx.x;
  int d = blockIdx.y*256 + tid;
  __shared__ float s_mask[NN];
  __shared__ float s_red[4];
  s_mask[tid] = amask[b*NN+tid];
  float cnt = blkReduceSum(s_mask[tid], s_red);
  const float* hb = h + (size_t)b*NN*DD + d;
  float a = 0.f;
  #pragma unroll 8
  for(int n=0;n<NN;n++) a += hb[(size_t)n*DD] * s_mask[n];
  arep[b*DD + d] = a/(cnt+1e-8f);
}

// ---------------------------------------------------------------------------
// Semantic prep B: sim[b][n] = cos(h[b,n,:], arep[b,:]). grid (64,64).
// ---------------------------------------------------------------------------
__global__ __launch_bounds__(256) void k_sim(const float* __restrict__ h,
    const float* __restrict__ arep, float* __restrict__ sim){
  int b = blockIdx.x, tid = threadIdx.x;
  int lane = tid&63, w = tid>>6;
  __shared__ __align__(16) float s_a[DD];
  __shared__ float s_red[4];
  float pa = 0.f;
  for(int d=tid; d<DD; d+=256){ float v = arep[b*DD+d]; s_a[d]=v; pa += v*v; }
  float na = blkReduceSum(pa, s_red);
  float nac = fmaxf(sqrtf(na), 1e-12f);
  int node = blockIdx.y*4 + w;
  const float* hr = h + ((size_t)b*NN+node)*DD;
  float dot=0.f, nn=0.f;
  #pragma unroll
  for(int q=0;q<3;q++){
    int c = lane*4 + q*256;
    float4 hv = *(const float4*)(hr + c);
    float4 av = *(const float4*)(s_a + c);
    dot += hv.x*av.x + hv.y*av.y + hv.z*av.z + hv.w*av.w;
    nn  += hv.x*hv.x + hv.y*hv.y + hv.z*hv.z + hv.w*hv.w;
  }
  for(int o=32;o>0;o>>=1){ dot += __shfl_down(dot,o,64); nn += __shfl_down(nn,o,64); }
  if(lane==0){
    nn = fmaxf(sqrtf(nn), 1e-12f);
    sim[b*NN+node] = dot/(nn*nac);
  }
}

// ---------------------------------------------------------------------------
// Semantic prep C: stable top-K per batch -> scattered v[b,:], S[b].
// ---------------------------------------------------------------------------
__global__ __launch_bounds__(256) void k_topk(const float* __restrict__ sim,
    float* __restrict__ vout, float* __restrict__ Sout){
  int b = blockIdx.x, tid = threadIdx.x;
  __shared__ float s_bv[4]; __shared__ int s_bi[4];
  __shared__ float s_tv[KK]; __shared__ int s_ti[KK];
  __shared__ float s_v[NN];
  float v = sim[b*NN+tid];
  int lane = tid&63, w = tid>>6;
  for(int k=0;k<KK;k++){
    float bv = v; int bi_ = tid;
    for(int o=32;o>0;o>>=1){
      float ov = __shfl_down(bv,o,64); int oi = __shfl_down(bi_,o,64);
      if(ov>bv || (ov==bv && oi<bi_)){ bv=ov; bi_=oi; }
    }
    if(lane==0){ s_bv[w]=bv; s_bi[w]=bi_; }
    __syncthreads();
    float gb = s_bv[0]; int gi = s_bi[0];
    for(int i=1;i<4;i++){ if(s_bv[i]>gb || (s_bv[i]==gb && s_bi[i]<gi)){ gb=s_bv[i]; gi=s_bi[i]; } }
    if(tid==0){ s_tv[k]=gb; s_ti[k]=gi; }
    if(tid==gi) v = -1e30f;
    __syncthreads();
  }
  s_v[tid]=0.f;
  __syncthreads();
  if(tid<KK) s_v[s_ti[tid]] = s_tv[tid];
  __syncthreads();
  float S=0.f;
  for(int k=0;k<KK;k++) S += s_tv[k];
  vout[b*NN+tid] = s_v[tid];
  if(tid==0) Sout[b] = S;
}

// ---------------------------------------------------------------------------
// Weight cast+transpose+pad: dst[n][k] bf16 [NPAD][KPAD] from W[k][300].
// ---------------------------------------------------------------------------
__global__ __launch_bounds__(256) void k_wcast(const float* __restrict__ W1,
    short* __restrict__ dst, int K, int KPAD, int NPAD){
  int idx = blockIdx.x*256 + threadIdx.x;
  if(idx >= NPAD*KPAD) return;
  int n = idx / KPAD, k = idx % KPAD;
  float v = (k < K && n < 300) ? W1[(size_t)k*300 + n] : 0.f;
  dst[idx] = f2bf(v);
}

// Quad pack for merged layer-0 GEMM: dst [1280][768], 4 segments of 320 rows:
// {syn0_W, syn0_tW, sem0_W, sem0_tW}, each 300 used + 20 zero pad.
__global__ __launch_bounds__(256) void k_wcast4(const float* __restrict__ W0,
    const float* __restrict__ W1, const float* __restrict__ W2,
    const float* __restrict__ W3, short* __restrict__ dst){
  int idx = blockIdx.x*256 + threadIdx.x;
  if(idx >= 1280*768) return;
  int n = idx / 768, k = idx - (n*768);
  int seg = n/320; int nl = n - seg*320;
  const float* src = (seg==0)?W0 : (seg==1)?W1 : (seg==2)?W2 : W3;
  float v = (nl<300) ? src[(size_t)k*300 + nl] : 0.f;
  dst[idx] = f2bf(v);
}

// ---------------------------------------------------------------------------
// MFMA GEMM. Y = X[M][KPAD] @ Wt^T, Wt[NPAD][KPAD] bf16. BM=64, BN=320, BK=32.
// ROUND-10 CHANGES:
//  (a) 2-phase double-buffered LDS (T3-minimum template): STAGE(t+1) is issued
//      BEFORE compute(t); ONE barrier per K-iter (its vmcnt(0) drain now lands
//      after the MFMA phase instead of immediately after DMA issue, so the
//      global->LDS latency hides under compute). LDS 52KB -> 3 blocks/CU,
//      which matches the existing register-limited occupancy (~3 waves/SIMD).
//  (b) bank-conflict fix: XOR swizzle key (row&3) -> ((row>>1)&3). With 64B
//      rows (16-bank stride) the old key left lanes {lo,lo+4,lo+8,...} on one
//      4-bank slot (8-way conflict, 2.94x). New key spreads lo=0..7 over all
//      eight 4-bank slots -> 4-way (1.58x), the floor for this access shape.
//      Applied identically on DMA source granule and ds_read position.
// ---------------------------------------------------------------------------
template<int KPAD, int MODE, typename XT>
__global__ __launch_bounds__(256,4) void k_gemm(const XT* __restrict__ X,
    const short* __restrict__ Bt, const int* __restrict__ positions,
    const float* __restrict__ posA, const float* __restrict__ posB,
    const float* __restrict__ tbA, const float* __restrict__ tbB,
    const float* __restrict__ a1A, const float* __restrict__ a2A,
    const float* __restrict__ a1B, const float* __restrict__ a2B,
    short* __restrict__ whbA, short* __restrict__ whbB,
    float* __restrict__ t1A, float* __restrict__ t1B,
    float* __restrict__ f1A, float* __restrict__ f2A,
    float* __restrict__ f1B, float* __restrict__ f2B,
    float* __restrict__ outf){
  __shared__ __align__(16) short sX[2][64*40];    // f32 path: stride 40; dma path: stride 32
  __shared__ __align__(16) short sB[2][320*32];
  __shared__ float sF1[64][2], sF2[64][2];
  const int tid = threadIdx.x;
  const int lane = tid & 63, wave = tid >> 6;
  const int rgrp = wave & 1, cgrp = wave >> 1;
  const int row0 = blockIdx.x * 64;
  const int ncol0 = blockIdx.y * 320;
  const int lo = lane & 31, hi = lane >> 5;
  constexpr int NIT = KPAD/32;
  const int phase = (int)((blockIdx.x*7 + blockIdx.y*3) % NIT);
  const int drow = lane>>2;                        // 0..15
  const int dk   = ((lane&3) ^ ((drow>>1)&3))*8;   // swizzled k-granule (shorts)
  const int rk   = (lo>>1)&3;                      // read-side XOR key (== (row>>1)&3)

  f32x16 acc[5];
  #pragma unroll
  for(int t=0;t<5;t++)
    #pragma unroll
    for(int i=0;i<16;i++) acc[t][i] = 0.f;

  float4 rx0, rx1;
  int cur = 0;

  // ---- prologue: stage tile it=0 into buf 0 ----
  {
    int kv = phase; int k0 = kv*32;
    if constexpr (sizeof(XT)==4){
      int c0=tid, c1=tid+256;
      rx0 = *(const float4*)(X + (size_t)(row0+(c0>>3))*KPAD + k0 + (c0&7)*4);
      rx1 = *(const float4*)(X + (size_t)(row0+(c1>>3))*KPAD + k0 + (c1&7)*4);
      { short4v s; s.x=f2bf(rx0.x); s.y=f2bf(rx0.y); s.z=f2bf(rx0.z); s.w=f2bf(rx0.w);
        *(short4v*)(sX[0] + (c0>>3)*40 + (c0&7)*4) = s; }
      { short4v s; s.x=f2bf(rx1.x); s.y=f2bf(rx1.y); s.z=f2bf(rx1.z); s.w=f2bf(rx1.w);
        *(short4v*)(sX[0] + (c1>>3)*40 + (c1&7)*4) = s; }
    } else {
      dma16(X + (size_t)(row0 + wave*16 + drow)*KPAD + k0 + dk, sX[0] + wave*512);
    }
    #pragma unroll
    for(int u=0;u<5;u++){
      int q = wave*5+u;
      dma16(Bt + (size_t)(ncol0 + q*16 + drow)*KPAD + k0 + dk, sB[0] + q*512);
    }
  }
  __syncthreads();
  if constexpr (sizeof(XT)==4){
    if(NIT>1){
      int kv = phase+1; if(kv>=NIT) kv-=NIT; int k1 = kv*32;
      int c0=tid, c1=tid+256;
      rx0 = *(const float4*)(X + (size_t)(row0+(c0>>3))*KPAD + k1 + (c0&7)*4);
      rx1 = *(const float4*)(X + (size_t)(row0+(c1>>3))*KPAD + k1 + (c1&7)*4);
    }
  }

  for(int it=0; it<NIT; it++){
    // ---- stage tile it+1 into buf[cur^1] (overlaps with compute below) ----
    if(it+1 < NIT){
      int nkv = it+1+phase; if(nkv >= NIT) nkv -= NIT;
      int nk0 = nkv*32;
      if constexpr (sizeof(XT)==4){
        { int c0=tid; short4v s; s.x=f2bf(rx0.x); s.y=f2bf(rx0.y); s.z=f2bf(rx0.z); s.w=f2bf(rx0.w);
          *(short4v*)(sX[cur^1] + (c0>>3)*40 + (c0&7)*4) = s; }
        { int c1=tid+256; short4v s; s.x=f2bf(rx1.x); s.y=f2bf(rx1.y); s.z=f2bf(rx1.z); s.w=f2bf(rx1.w);
          *(short4v*)(sX[cur^1] + (c1>>3)*40 + (c1&7)*4) = s; }
      } else {
        dma16(X + (size_t)(row0 + wave*16 + drow)*KPAD + nk0 + dk, sX[cur^1] + wave*512);
      }
      #pragma unroll
      for(int u=0;u<5;u++){
        int q = wave*5+u;
        dma16(Bt + (size_t)(ncol0 + q*16 + drow)*KPAD + nk0 + dk, sB[cur^1] + q*512);
      }
      if constexpr (sizeof(XT)==4){
        if(it+2 < NIT){
          int kv2 = it+2+phase; if(kv2 >= NIT) kv2 -= NIT; int k2 = kv2*32;
          int c0=tid, c1=tid+256;
          rx0 = *(const float4*)(X + (size_t)(row0+(c0>>3))*KPAD + k2 + (c0&7)*4);
          rx1 = *(const float4*)(X + (size_t)(row0+(c1>>3))*KPAD + k2 + (c1&7)*4);
        }
      }
    }
    // ---- compute tile it from buf[cur] ----
    #pragma unroll
    for(int ss=0; ss<2; ss++){
      short8 a;
      if constexpr (sizeof(XT)==4){
        a = *(const short8*)(sX[cur] + (rgrp*32 + lo)*40 + ss*16 + hi*8);
      } else {
        a = *(const short8*)(sX[cur] + (rgrp*32 + lo)*32 + (((ss*2+hi)^rk)*8));
      }
      #pragma unroll
      for(int t=0;t<5;t++){
        short8 b = *(const short8*)(sB[cur] + (cgrp*160 + t*32 + lo)*32 + (((ss*2+hi)^rk)*8));
        acc[t] = __builtin_amdgcn_mfma_f32_32x32x16_bf16(a, b, acc[t], 0, 0, 0);
      }
    }
    __syncthreads();   // single barrier/iter: drains DMA(t+1) after compute(t)
    cur ^= 1;
  }

  // ---- epilogue ----
  const int seg = (MODE==3) ? blockIdx.y : 0;
  const bool fold = (MODE==0) || (MODE==3 && (seg==0 || seg==2));
  float* sAv = (float*)sB;   // reuse LDS for a1/a2 cache (last barrier passed)
  if(fold){
    const float* a1v = (MODE==3 && seg==2) ? a1B : a1A;
    const float* a2v = (MODE==3 && seg==2) ? a2B : a2A;
    for(int c=tid; c<300; c+=256){ sAv[c] = a1v[c]; sAv[c+300] = a2v[c]; }
    __syncthreads();
  }
  #pragma unroll
  for(int r=0;r<16;r++){
    int lr = rgrp*32 + (r&3) + 8*(r>>2) + 4*hi;
    int row = row0 + lr;
    int p = (MODE!=2) ? positions[row] : 0;
    float s1=0.f, s2=0.f;
    #pragma unroll
    for(int t=0;t<5;t++){
      int nc = cgrp*160 + t*32 + lo;
      float v = acc[t][r];
      if(nc < 300){
        if(MODE==2){
          outf[(size_t)row*300 + nc] = fmaxf(v + tbA[nc], 0.f);
        } else if(MODE==0){
          float y = v + posA[(size_t)p*300 + nc];
          whbA[(size_t)row*320 + nc] = f2bf(y);
          s1 += y*sAv[nc]; s2 += y*sAv[300+nc];
        } else { // MODE 3
          if(seg==0){
            float y = v + posA[(size_t)p*300 + nc];
            whbA[(size_t)row*320 + nc] = f2bf(y);
            s1 += y*sAv[nc]; s2 += y*sAv[300+nc];
          } else if(seg==1){
            t1A[(size_t)row*300 + nc] = v + tbA[nc];
          } else if(seg==2){
            float y = v + posB[(size_t)p*300 + nc];
            whbB[(size_t)row*320 + nc] = f2bf(y);
            s1 += y*sAv[nc]; s2 += y*sAv[300+nc];
          } else {
            t1B[(size_t)row*300 + nc] = v + tbB[nc];
          }
        }
      }
    }
    if(fold){
      for(int o=1;o<32;o<<=1){ s1 += __shfl_xor(s1,o,64); s2 += __shfl_xor(s2,o,64); }
      if(lo==0){ sF1[lr][cgrp] = s1; sF2[lr][cgrp] = s2; }
    }
  }
  if(fold){
    __syncthreads();
    if(tid < 64){
      float* f1o = (MODE==3 && seg==2) ? f1B : f1A;
      float* f2o = (MODE==3 && seg==2) ? f2B : f2A;
      f1o[row0+tid] = sF1[tid][0] + sF1[tid][1];
      f2o[row0+tid] = sF2[tid][0] + sF2[tid][1];
    }
  }
}

// ---------------------------------------------------------------------------
// Pure Wh transpose: WhT[b][n(320)][j(256)] bf16 from Whb[row][320] bf16.
// ---------------------------------------------------------------------------
__global__ __launch_bounds__(256) void k_whT(const short* __restrict__ Whb,
    short* __restrict__ WhT){
  __shared__ short s_t[64][308];
  int b = blockIdx.x, j0 = blockIdx.y*64, tid = threadIdx.x;
  for(int c=tid; c<64*300; c+=256){
    int r = c/300, n = c - r*300;
    s_t[r][n] = Whb[((size_t)(b*NN + j0 + r))*320 + n];
  }
  __syncthreads();
  for(int c=tid; c<320*64; c+=256){
    int n = c>>6, jj = c&63;
    WhT[((size_t)b*320 + n)*256 + j0 + jj] = (n<GG) ? s_t[jj][n] : (short)0;
  }
}

// ---------------------------------------------------------------------------
// Fused attention (MFMA) + residual + LayerNorm + ReLU. grid (64,4), 256 thr.
// ROUND-10: same 2-phase dbuf restructure for the PV loop (stage k0+32 before
// MFMA(k0), single barrier per step); prologue stage of k0=0 is issued before
// the score phase so its latency hides under the exp/softmax work.
// ---------------------------------------------------------------------------
template<bool SEM>
__global__ __launch_bounds__(256) void k_attn_ln(
    const short* __restrict__ WhT,
    const float* __restrict__ f1, const float* __restrict__ f2,
    const int* __restrict__ adjI, const float* __restrict__ vvec,
    const float* __restrict__ Svec,
    const float* __restrict__ resf, const short* __restrict__ resb,
    const float* __restrict__ g, const float* __restrict__ bt,
    short* __restrict__ bfout, int bf_ld, int bf_off, int bfpad){
  int b = blockIdx.x, i0 = blockIdx.y*64, tid = threadIdx.x;
  int lane = tid&63, wave = tid>>6;
  int lo = lane&31, hi = lane>>5;
  int rgrp = wave&1, cgrp = wave>>1;

  __shared__ float s_f2[NN];
  __shared__ float s_v[NN];
  __shared__ float s_inv[64];
  __shared__ float sRed[64][2];
  __shared__ __align__(16) short sP[64][264];
  __shared__ __align__(16) short sB[2][320*40];

  s_f2[tid] = f2[b*NN+tid];
  float S = 0.f;
  if(SEM){ s_v[tid] = vvec[b*NN+tid]; S = Svec[b]; }

  const short* wtb = WhT + (size_t)b*320*256;
  // prologue: stage k0=0 into sB[0]; latency hides under the score phase
  #pragma unroll
  for(int u=0;u<5;u++){
    int c = tid + u*256; int r=c>>2, cc=c&3;
    *(short8*)(sB[0] + r*40 + cc*8) = *(const short8*)(wtb + (size_t)r*256 + cc*8);
  }
  __syncthreads();

  {
    int r = tid>>2, q = tid&3, i = i0 + r;
    float fi = f1[b*NN+i];
    float vi = 0.f, denom = 0.f;
    if(SEM){ vi = s_v[i]; denom = 0.5f*((float)NN*vi + S) + 1.f + 1e-8f; }
    const int* arow = adjI ? (adjI + ((size_t)b*NN+i)*NN + q*64) : (const int*)0;
    float s = 0.f;
    #pragma unroll
    for(int c=0;c<8;c++){
      int jb = q*64 + c*8;
      int4 a0, a1_;
      if(!SEM){ a0 = *(const int4*)(arow + c*8); a1_ = *(const int4*)(arow + c*8 + 4); }
      short8 ps;
      #pragma unroll
      for(int k=0;k<8;k++){
        int j = jb + k;
        float ee = fi + s_f2[j];
        ee = ee>0.f ? ee : 0.2f*ee;
        bool m;
        if(SEM){
          float val = 0.5f*(vi + s_v[j]) + (i==j ? 1.f : 0.f);
          m = (denom > 0.f) ? (val > 0.f) : (val < 0.f);
        } else {
          m = ((k<4) ? (&a0.x)[k] : (&a1_.x)[k-4]) > 0;
        }
        float pv = m ? __expf(ee) : 0.f;
        s += pv;
        ps[k] = f2bf(pv);
      }
      *(short8*)&sP[r][jb] = ps;
    }
    s += __shfl_xor(s,1,64);
    s += __shfl_xor(s,2,64);
    if(q==0) s_inv[r] = 1.f/s;
  }
  __syncthreads();

  f32x16 acc[5];
  #pragma unroll
  for(int t=0;t<5;t++)
    #pragma unroll
    for(int i=0;i<16;i++) acc[t][i] = 0.f;

  int cur = 0;
  for(int k0=0; k0<256; k0+=32){
    // stage next k-slab into buf[cur^1]; overlaps with MFMA below
    if(k0+32 < 256){
      #pragma unroll
      for(int u=0;u<5;u++){
        int c = tid + u*256; int r=c>>2, cc=c&3;
        *(short8*)(sB[cur^1] + r*40 + cc*8) = *(const short8*)(wtb + (size_t)r*256 + (k0+32) + cc*8);
      }
    }
    #pragma unroll
    for(int ss=0; ss<2; ss++){
      short8 a = *(const short8*)&sP[rgrp*32 + lo][k0 + ss*16 + hi*8];
      #pragma unroll
      for(int t=0;t<5;t++){
        short8 bb = *(const short8*)(sB[cur] + (cgrp*160 + t*32 + lo)*40 + ss*16 + hi*8);
        acc[t] = __builtin_amdgcn_mfma_f32_32x32x16_bf16(a, bb, acc[t], 0, 0, 0);
      }
    }
    __syncthreads();   // single barrier per step
    cur ^= 1;
  }

  #pragma unroll
  for(int r=0;r<16;r++){
    int lr = rgrp*32 + (r&3) + 8*(r>>2) + 4*hi;
    float inv_s = s_inv[lr];
    size_t grow = (size_t)(b*NN + i0 + lr);
    float sum = 0.f;
    #pragma unroll
    for(int t=0;t<5;t++){
      int nc = cgrp*160 + t*32 + lo;
      float x = 0.f;
      if(nc < GG){
        float rv = resf ? resf[grow*300 + nc] : bf2f(resb[grow*320 + nc]);
        x = acc[t][r]*inv_s + rv;
      }
      acc[t][r] = x; sum += x;
    }
    for(int o=1;o<32;o<<=1) sum += __shfl_xor(sum,o,64);
    if(lo==0) sRed[lr][cgrp] = sum;
  }
  __syncthreads();
  float mean[16];
  #pragma unroll
  for(int r=0;r<16;r++){
    int lr = rgrp*32 + (r&3) + 8*(r>>2) + 4*hi;
    mean[r] = (sRed[lr][0] + sRed[lr][1]) * (1.f/(float)GG);
  }
  __syncthreads();
  #pragma unroll
  for(int r=0;r<16;r++){
    int lr = rgrp*32 + (r&3) + 8*(r>>2) + 4*hi;
    float s = 0.f;
    #pragma unroll
    for(int t=0;t<5;t++){
      int nc = cgrp*160 + t*32 + lo;
      if(nc < GG){ float d = acc[t][r] - mean[r]; s += d*d; }
    }
    for(int o=1;o<32;o<<=1) s += __shfl_xor(s,o,64);
    if(lo==0) sRed[lr][cgrp] = s;
  }
  __syncthreads();
  #pragma unroll
  for(int r=0;r<16;r++){
    int lr = rgrp*32 + (r&3) + 8*(r>>2) + 4*hi;
    size_t grow = (size_t)(b*NN + i0 + lr);
    float iv = 1.0f/sqrtf((sRed[lr][0]+sRed[lr][1])/(float)GG + 1e-5f);
    float mn = mean[r];
    #pragma unroll
    for(int t=0;t<5;t++){
      int nc = cgrp*160 + t*32 + lo;
      if(nc < GG){
        float y = fmaxf((acc[t][r]-mn)*iv*g[nc] + bt[nc], 0.f);
        bfout[grow*bf_ld + bf_off + nc] = f2bf(y);
      } else if(nc < bfpad){
        bfout[grow*bf_ld + bf_off + nc] = 0;
      }
    }
  }
}

// ---------------------------------------------------------------------------
extern "C" void kernel_launch(void* const* d_in, const int* in_sizes, int n_in,
                              void* d_out, int out_size, void* d_ws, size_t ws_size,
                              hipStream_t stream){
  const float* h     = (const float*)d_in[0];
  const float* amask = (const float*)d_in[1];
  const float *syn0_W=(const float*)d_in[2], *syn0_a1=(const float*)d_in[3], *syn0_a2=(const float*)d_in[4],
              *syn0_pos=(const float*)d_in[5], *syn0_tW=(const float*)d_in[6], *syn0_tb=(const float*)d_in[7],
              *syn0_g=(const float*)d_in[8], *syn0_b=(const float*)d_in[9];
  const float *syn1_W=(const float*)d_in[10], *syn1_a1=(const float*)d_in[11], *syn1_a2=(const float*)d_in[12],
              *syn1_pos=(const float*)d_in[13], *syn1_g=(const float*)d_in[14], *syn1_b=(const float*)d_in[15];
  const float *sem0_W=(const float*)d_in[16], *sem0_a1=(const float*)d_in[17], *sem0_a2=(const float*)d_in[18],
              *sem0_pos=(const float*)d_in[19], *sem0_tW=(const float*)d_in[20], *sem0_tb=(const float*)d_in[21],
              *sem0_g=(const float*)d_in[22], *sem0_b=(const float*)d_in[23];
  const float *sem1_W=(const float*)d_in[24], *sem1_a1=(const float*)d_in[25], *sem1_a2=(const float*)d_in[26],
              *sem1_pos=(const float*)d_in[27], *sem1_g=(const float*)d_in[28], *sem1_b=(const float*)d_in[29];
  const float *fus_W=(const float*)d_in[30], *fus_b=(const float*)d_in[31];
  const int* synadj    = (const int*)d_in[32];
  const int* positions = (const int*)d_in[33];
  float* out = (float*)d_out;

  float* ws   = (float*)d_ws;
  float* vvec = ws;                    // 16384
  float* Svec = vvec + 16384;          // 64
  float* f1a  = Svec + 64;             // 16384
  float* f2a  = f1a + 16384;           // 16384
  float* f1b  = f2a + 16384;           // 16384
  float* f2b  = f1b + 16384;           // 16384
  float* arep = f2b + 16384;           // 49152
  float* simb = arep + 49152;          // 16384
  float* T1_syn = simb + 16384;        // 4,915,200
  float* T1_sem = T1_syn + 4915200;    // 4,915,200
  short* Whb_syn = (short*)(T1_sem + 4915200);  // [16384][320]
  short* Whb_sem = Whb_syn + 5242880;
  short* Xb      = Whb_sem + 5242880;  // [16384][320]
  short* WhT     = Xb + 5242880;       // [64][320][256]
  short* Xf      = WhT + 5242880;      // [16384][608]
  short* Wt_all  = Xf + 9961472;       // [1280][768]
  short* Wt_syn1 = Wt_all + 983040;    // [320][320]
  short* Wt_sem1 = Wt_syn1 + 102400;
  short* Wt_fus  = Wt_sem1 + 102400;   // [320][608]

  dim3 gAttn(BB, 4), gWT(BB, 4);
  dim3 gG4(256, 4), gG1(256, 1);

  // semantic prep
  k_arep<<<dim3(BB,3),256,0,stream>>>(h, amask, arep);
  k_sim <<<dim3(BB,64),256,0,stream>>>(h, arep, simb);
  k_topk<<<BB,256,0,stream>>>(simb, vvec, Svec);

  // weight packs
  k_wcast4<<<3840,256,0,stream>>>(syn0_W, syn0_tW, sem0_W, sem0_tW, Wt_all);
  k_wcast<<<400,256,0,stream>>>(syn1_W, Wt_syn1, 300, 320, 320);
  k_wcast<<<400,256,0,stream>>>(sem1_W, Wt_sem1, 300, 320, 320);
  k_wcast<<<760,256,0,stream>>>(fus_W,  Wt_fus,  600, 608, 320);

  // merged layer-0 GEMM: Wh (bf16) + residuals (f32) + folded f1/f2 per channel
  k_gemm<768,3,float><<<gG4,256,0,stream>>>(h, Wt_all, positions,
      syn0_pos, sem0_pos, syn0_tb, sem0_tb,
      syn0_a1, syn0_a2, sem0_a1, sem0_a2,
      Whb_syn, Whb_sem, T1_syn, T1_sem,
      f1a, f2a, f1b, f2b, nullptr);

  // ---- syntactic channel ----
  k_whT<<<gWT,256,0,stream>>>(Whb_syn, WhT);
  k_attn_ln<false><<<gAttn,256,0,stream>>>(WhT, f1a, f2a, synadj, nullptr, nullptr,
      T1_syn, nullptr, syn0_g, syn0_b, Xb, 320, 0, 320);
  k_gemm<320,0,short><<<gG1,256,0,stream>>>(Xb, Wt_syn1, positions,
      syn1_pos, nullptr, nullptr, nullptr,
      syn1_a1, syn1_a2, nullptr, nullptr,
      Whb_syn, nullptr, nullptr, nullptr,
      f1a, f2a, nullptr, nullptr, nullptr);
  k_whT<<<gWT,256,0,stream>>>(Whb_syn, WhT);
  k_attn_ln<false><<<gAttn,256,0,stream>>>(WhT, f1a, f2a, synadj, nullptr, nullptr,
      nullptr, Xb, syn1_g, syn1_b, Xf, 608, 0, 300);

  // ---- semantic channel ----
  k_whT<<<gWT,256,0,stream>>>(Whb_sem, WhT);
  k_attn_ln<true><<<gAttn,256,0,stream>>>(WhT, f1b, f2b, nullptr, vvec, Svec,
      T1_sem, nullptr, sem0_g, sem0_b, Xb, 320, 0, 320);
  k_gemm<320,0,short><<<gG1,256,0,stream>>>(Xb, Wt_sem1, positions,
      sem1_pos, nullptr, nullptr, nullptr,
      sem1_a1, sem1_a2, nullptr, nullptr,
      Whb_sem, nullptr, nullptr, nullptr,
      f1b, f2b, nullptr, nullptr, nullptr);
  k_whT<<<gWT,256,0,stream>>>(Whb_sem, WhT);
  k_attn_ln<true><<<gAttn,256,0,stream>>>(WhT, f1b, f2b, nullptr, vvec, Svec,
      nullptr, Xb, sem1_g, sem1_b, Xf, 608, 300, 308);

  // fusion: out = relu(concat @ fus_W + fus_b)
  k_gemm<608,2,short><<<gG1,256,0,stream>>>(Xf, Wt_fus, positions,
      nullptr, nullptr, fus_b, nullptr,
      nullptr, nullptr, nullptr, nullptr,
      nullptr, nullptr, nullptr, nullptr,
      nullptr, nullptr, nullptr, nullptr, out);
}

// Round 3
// 538.854 us; speedup vs baseline: 1.3885x; 1.3885x over previous
//
#include <hip/hip_runtime.h>
#include <hip/hip_bf16.h>
#include <math.h>

#define BB 64
#define NN 256
#define DD 768
#define GG 300
#define KK 10
#define NEGV -9e15f

typedef __attribute__((ext_vector_type(8)))  short short8;
typedef __attribute__((ext_vector_type(4)))  short short4v;
typedef __attribute__((ext_vector_type(16))) float f32x16;

static __device__ __forceinline__ short f2bf(float f){
  __hip_bfloat16 b = __float2bfloat16(f);
  return __builtin_bit_cast(short, b);
}
static __device__ __forceinline__ float bf2f(short s){
  return __bfloat162float(__builtin_bit_cast(__hip_bfloat16, s));
}

// async global->LDS DMA, 16B per lane; dst is wave-uniform base (+lane*16 by HW)
static __device__ __forceinline__ void dma16(const void* g, void* l){
  __builtin_amdgcn_global_load_lds((const __attribute__((address_space(1))) void*)g,
                                   (__attribute__((address_space(3))) void*)l, 16, 0, 0);
}

__device__ __forceinline__ float blkReduceSum(float v, float* s){
  for(int o=32;o>0;o>>=1) v += __shfl_down(v,o,64);
  int nw = blockDim.x>>6;
  __syncthreads();
  if((threadIdx.x&63)==0) s[threadIdx.x>>6]=v;
  __syncthreads();
  float r=s[0];
  for(int i=1;i<nw;i++) r+=s[i];
  return r;
}

// ---------------------------------------------------------------------------
// Semantic prep A: arep[b][d] = masked mean of h over nodes. grid (64,3).
// ---------------------------------------------------------------------------
__global__ __launch_bounds__(256) void k_arep(const float* __restrict__ h,
    const float* __restrict__ amask, float* __restrict__ arep){
  int b = blockIdx.x, tid = threadIdx.x;
  int d = blockIdx.y*256 + tid;
  __shared__ float s_mask[NN];
  __shared__ float s_red[4];
  s_mask[tid] = amask[b*NN+tid];
  float cnt = blkReduceSum(s_mask[tid], s_red);
  const float* hb = h + (size_t)b*NN*DD + d;
  float a = 0.f;
  #pragma unroll 8
  for(int n=0;n<NN;n++) a += hb[(size_t)n*DD] * s_mask[n];
  arep[b*DD + d] = a/(cnt+1e-8f);
}

// ---------------------------------------------------------------------------
// Semantic prep B: sim[b][n] = cos(h[b,n,:], arep[b,:]). grid (64,64).
// ---------------------------------------------------------------------------
__global__ __launch_bounds__(256) void k_sim(const float* __restrict__ h,
    const float* __restrict__ arep, float* __restrict__ sim){
  int b = blockIdx.x, tid = threadIdx.x;
  int lane = tid&63, w = tid>>6;
  __shared__ __align__(16) float s_a[DD];
  __shared__ float s_red[4];
  float pa = 0.f;
  for(int d=tid; d<DD; d+=256){ float v = arep[b*DD+d]; s_a[d]=v; pa += v*v; }
  float na = blkReduceSum(pa, s_red);
  float nac = fmaxf(sqrtf(na), 1e-12f);
  int node = blockIdx.y*4 + w;
  const float* hr = h + ((size_t)b*NN+node)*DD;
  float dot=0.f, nn=0.f;
  #pragma unroll
  for(int q=0;q<3;q++){
    int c = lane*4 + q*256;
    float4 hv = *(const float4*)(hr + c);
    float4 av = *(const float4*)(s_a + c);
    dot += hv.x*av.x + hv.y*av.y + hv.z*av.z + hv.w*av.w;
    nn  += hv.x*hv.x + hv.y*hv.y + hv.z*hv.z + hv.w*hv.w;
  }
  for(int o=32;o>0;o>>=1){ dot += __shfl_down(dot,o,64); nn += __shfl_down(nn,o,64); }
  if(lane==0){
    nn = fmaxf(sqrtf(nn), 1e-12f);
    sim[b*NN+node] = dot/(nn*nac);
  }
}

// ---------------------------------------------------------------------------
// Semantic prep C: stable top-K per batch -> scattered v[b,:], S[b].
// ---------------------------------------------------------------------------
__global__ __launch_bounds__(256) void k_topk(const float* __restrict__ sim,
    float* __restrict__ vout, float* __restrict__ Sout){
  int b = blockIdx.x, tid = threadIdx.x;
  __shared__ float s_bv[4]; __shared__ int s_bi[4];
  __shared__ float s_tv[KK]; __shared__ int s_ti[KK];
  __shared__ float s_v[NN];
  float v = sim[b*NN+tid];
  int lane = tid&63, w = tid>>6;
  for(int k=0;k<KK;k++){
    float bv = v; int bi_ = tid;
    for(int o=32;o>0;o>>=1){
      float ov = __shfl_down(bv,o,64); int oi = __shfl_down(bi_,o,64);
      if(ov>bv || (ov==bv && oi<bi_)){ bv=ov; bi_=oi; }
    }
    if(lane==0){ s_bv[w]=bv; s_bi[w]=bi_; }
    __syncthreads();
    float gb = s_bv[0]; int gi = s_bi[0];
    for(int i=1;i<4;i++){ if(s_bv[i]>gb || (s_bv[i]==gb && s_bi[i]<gi)){ gb=s_bv[i]; gi=s_bi[i]; } }
    if(tid==0){ s_tv[k]=gb; s_ti[k]=gi; }
    if(tid==gi) v = -1e30f;
    __syncthreads();
  }
  s_v[tid]=0.f;
  __syncthreads();
  if(tid<KK) s_v[s_ti[tid]] = s_tv[tid];
  __syncthreads();
  float S=0.f;
  for(int k=0;k<KK;k++) S += s_tv[k];
  vout[b*NN+tid] = s_v[tid];
  if(tid==0) Sout[b] = S;
}

// ---------------------------------------------------------------------------
// Weight cast+transpose+pad: dst[n][k] bf16 [NPAD][KPAD] from W[k][300].
// ---------------------------------------------------------------------------
__global__ __launch_bounds__(256) void k_wcast(const float* __restrict__ W1,
    short* __restrict__ dst, int K, int KPAD, int NPAD){
  int idx = blockIdx.x*256 + threadIdx.x;
  if(idx >= NPAD*KPAD) return;
  int n = idx / KPAD, k = idx % KPAD;
  float v = (k < K && n < 300) ? W1[(size_t)k*300 + n] : 0.f;
  dst[idx] = f2bf(v);
}

// Quad pack for merged layer-0 GEMM: dst [1280][768], 4 segments of 320 rows:
// {syn0_W, syn0_tW, sem0_W, sem0_tW}, each 300 used + 20 zero pad.
__global__ __launch_bounds__(256) void k_wcast4(const float* __restrict__ W0,
    const float* __restrict__ W1, const float* __restrict__ W2,
    const float* __restrict__ W3, short* __restrict__ dst){
  int idx = blockIdx.x*256 + threadIdx.x;
  if(idx >= 1280*768) return;
  int n = idx / 768, k = idx - (n*768);
  int seg = n/320; int nl = n - seg*320;
  const float* src = (seg==0)?W0 : (seg==1)?W1 : (seg==2)?W2 : W3;
  float v = (nl<300) ? src[(size_t)k*300 + nl] : 0.f;
  dst[idx] = f2bf(v);
}

// ---------------------------------------------------------------------------
// MFMA GEMM. Y = X[M][KPAD] @ Wt^T, Wt[NPAD][KPAD] bf16. BM=64, BN=320, BK=32.
// Single-buffer schedule (4 blocks/CU inter-block overlap), bank-conflict
// XOR key ((row>>1)&3) on both DMA-source granule and ds_read position.
// MODE 0 z-merged over channels; T1 residuals written bf16.
// ---------------------------------------------------------------------------
template<int KPAD, int MODE, typename XT>
__global__ __launch_bounds__(256,4) void k_gemm(const XT* __restrict__ X,
    const short* __restrict__ Bt,
    const XT* __restrict__ X2, const short* __restrict__ Bt2,
    const int* __restrict__ positions,
    const float* __restrict__ posA, const float* __restrict__ posB,
    const float* __restrict__ tbA, const float* __restrict__ tbB,
    const float* __restrict__ a1A, const float* __restrict__ a2A,
    const float* __restrict__ a1B, const float* __restrict__ a2B,
    short* __restrict__ whbA, short* __restrict__ whbB,
    short* __restrict__ t1A, short* __restrict__ t1B,
    float* __restrict__ f1A, float* __restrict__ f2A,
    float* __restrict__ f1B, float* __restrict__ f2B,
    float* __restrict__ outf){
  __shared__ __align__(16) short sX[64*40];
  __shared__ __align__(16) short sB[320*32];
  __shared__ float sF1[64][2], sF2[64][2];
  const int tid = threadIdx.x;
  const int lane = tid & 63, wave = tid >> 6;
  const int rgrp = wave & 1, cgrp = wave >> 1;
  const int row0 = blockIdx.x * 64;
  const int ncol0 = blockIdx.y * 320;
  const int lo = lane & 31, hi = lane >> 5;
  constexpr int NIT = KPAD/32;
  const int phase = (int)((blockIdx.x*7 + blockIdx.y*3) % NIT);
  const int drow = lane>>2;                        // 0..15
  const int dk   = ((lane&3) ^ ((drow>>1)&3))*8;   // swizzled k-granule (shorts)
  const int rk   = (lo>>1)&3;                      // read-side XOR key

  // channel selection for merged MODE 0 (blockIdx.z)
  const XT* Xp = X; const short* Btp = Bt;
  const float *posS=posA, *a1S=a1A, *a2S=a2A;
  short* whbS=whbA; float *f1S=f1A, *f2S=f2A;
  if constexpr (MODE==0){
    if(blockIdx.z==1){ Xp=X2; Btp=Bt2; posS=posB; a1S=a1B; a2S=a2B; whbS=whbB; f1S=f1B; f2S=f2B; }
  }

  f32x16 acc[5];
  #pragma unroll
  for(int t=0;t<5;t++)
    #pragma unroll
    for(int i=0;i<16;i++) acc[t][i] = 0.f;

  float4 rx0, rx1;
  if constexpr (sizeof(XT)==4){
    int k0 = phase*32;
    int c0=tid, c1=tid+256;
    rx0 = *(const float4*)(Xp + (size_t)(row0+(c0>>3))*KPAD + k0 + (c0&7)*4);
    rx1 = *(const float4*)(Xp + (size_t)(row0+(c1>>3))*KPAD + k0 + (c1&7)*4);
  }

  for(int it=0; it<NIT; it++){
    int kv = it + phase; if(kv >= NIT) kv -= NIT;
    int k0 = kv*32;
    if constexpr (sizeof(XT)==4){
      { int c=tid; short4v s; s.x=f2bf(rx0.x); s.y=f2bf(rx0.y); s.z=f2bf(rx0.z); s.w=f2bf(rx0.w);
        *(short4v*)(sX + (c>>3)*40 + (c&7)*4) = s; }
      { int c=tid+256; short4v s; s.x=f2bf(rx1.x); s.y=f2bf(rx1.y); s.z=f2bf(rx1.z); s.w=f2bf(rx1.w);
        *(short4v*)(sX + (c>>3)*40 + (c&7)*4) = s; }
    } else {
      dma16(Xp + (size_t)(row0 + wave*16 + drow)*KPAD + k0 + dk, sX + wave*512);
    }
    #pragma unroll
    for(int u=0;u<5;u++){
      int q = wave*5+u;
      dma16(Btp + (size_t)(ncol0 + q*16 + drow)*KPAD + k0 + dk, sB + q*512);
    }
    __syncthreads();
    if constexpr (sizeof(XT)==4){
      if(it+1 < NIT){
        int kn = it+1+phase; if(kn >= NIT) kn -= NIT;
        int k1 = kn*32;
        int c0=tid, c1=tid+256;
        rx0 = *(const float4*)(Xp + (size_t)(row0+(c0>>3))*KPAD + k1 + (c0&7)*4);
        rx1 = *(const float4*)(Xp + (size_t)(row0+(c1>>3))*KPAD + k1 + (c1&7)*4);
      }
    }
    #pragma unroll
    for(int ss=0; ss<2; ss++){
      short8 a;
      if constexpr (sizeof(XT)==4){
        a = *(const short8*)(sX + (rgrp*32 + lo)*40 + ss*16 + hi*8);
      } else {
        a = *(const short8*)(sX + (rgrp*32 + lo)*32 + (((ss*2+hi)^rk)*8));
      }
      #pragma unroll
      for(int t=0;t<5;t++){
        short8 b = *(const short8*)(sB + (cgrp*160 + t*32 + lo)*32 + (((ss*2+hi)^rk)*8));
        acc[t] = __builtin_amdgcn_mfma_f32_32x32x16_bf16(a, b, acc[t], 0, 0, 0);
      }
    }
    __syncthreads();
  }

  // ---- epilogue ----
  const int seg = (MODE==3) ? blockIdx.y : 0;
  const bool fold = (MODE==0) || (MODE==3 && (seg==0 || seg==2));
  float* sAv = (float*)sB;   // reuse LDS for a1/a2 cache (last barrier passed)
  if(fold){
    const float* a1v; const float* a2v;
    if constexpr (MODE==0){ a1v = a1S; a2v = a2S; }
    else { a1v = (seg==2) ? a1B : a1A; a2v = (seg==2) ? a2B : a2A; }
    for(int c=tid; c<300; c+=256){ sAv[c] = a1v[c]; sAv[c+300] = a2v[c]; }
    __syncthreads();
  }
  #pragma unroll
  for(int r=0;r<16;r++){
    int lr = rgrp*32 + (r&3) + 8*(r>>2) + 4*hi;
    int row = row0 + lr;
    int p = (MODE!=2) ? positions[row] : 0;
    float s1=0.f, s2=0.f;
    #pragma unroll
    for(int t=0;t<5;t++){
      int nc = cgrp*160 + t*32 + lo;
      float v = acc[t][r];
      if(nc < 300){
        if(MODE==2){
          outf[(size_t)row*300 + nc] = fmaxf(v + tbA[nc], 0.f);
        } else if(MODE==0){
          float y = v + posS[(size_t)p*300 + nc];
          whbS[(size_t)row*320 + nc] = f2bf(y);
          s1 += y*sAv[nc]; s2 += y*sAv[300+nc];
        } else { // MODE 3
          if(seg==0){
            float y = v + posA[(size_t)p*300 + nc];
            whbA[(size_t)row*320 + nc] = f2bf(y);
            s1 += y*sAv[nc]; s2 += y*sAv[300+nc];
          } else if(seg==1){
            t1A[(size_t)row*320 + nc] = f2bf(v + tbA[nc]);
          } else if(seg==2){
            float y = v + posB[(size_t)p*300 + nc];
            whbB[(size_t)row*320 + nc] = f2bf(y);
            s1 += y*sAv[nc]; s2 += y*sAv[300+nc];
          } else {
            t1B[(size_t)row*320 + nc] = f2bf(v + tbB[nc]);
          }
        }
      }
    }
    if(fold){
      for(int o=1;o<32;o<<=1){ s1 += __shfl_xor(s1,o,64); s2 += __shfl_xor(s2,o,64); }
      if(lo==0){ sF1[lr][cgrp] = s1; sF2[lr][cgrp] = s2; }
    }
  }
  if(fold){
    __syncthreads();
    if(tid < 64){
      float* f1o; float* f2o;
      if constexpr (MODE==0){ f1o = f1S; f2o = f2S; }
      else { f1o = (seg==2) ? f1B : f1A; f2o = (seg==2) ? f2B : f2A; }
      f1o[row0+tid] = sF1[tid][0] + sF1[tid][1];
      f2o[row0+tid] = sF2[tid][0] + sF2[tid][1];
    }
  }
}

// ---------------------------------------------------------------------------
// Pure Wh transpose, z-merged over channels: grid (64,4,2).
// ---------------------------------------------------------------------------
__global__ __launch_bounds__(256) void k_whT(const short* __restrict__ WhbA,
    const short* __restrict__ WhbB, short* __restrict__ WhTA,
    short* __restrict__ WhTB){
  const short* Whb = blockIdx.z ? WhbB : WhbA;
  short* WhT = blockIdx.z ? WhTB : WhTA;
  __shared__ short s_t[64][308];
  int b = blockIdx.x, j0 = blockIdx.y*64, tid = threadIdx.x;
  for(int c=tid; c<64*300; c+=256){
    int r = c/300, n = c - r*300;
    s_t[r][n] = Whb[((size_t)(b*NN + j0 + r))*320 + n];
  }
  __syncthreads();
  for(int c=tid; c<320*64; c+=256){
    int n = c>>6, jj = c&63;
    WhT[((size_t)b*320 + n)*256 + j0 + jj] = (n<GG) ? s_t[jj][n] : (short)0;
  }
}

// ---------------------------------------------------------------------------
// Fused attention (MFMA) + residual(bf16) + LayerNorm + ReLU.
// z-merged over channels: grid (64,4,2); z=0 syn (adj mask), z=1 sem.
// LDS ~62KB (single-buffer sB) so 2 blocks/CU fit.
// ---------------------------------------------------------------------------
struct AttnSmem {
  float s_f2[NN];
  float s_v[NN];
  float s_inv[64];
  float sRed[64][2];
  alignas(16) short sP[64][264];
  alignas(16) short sB[320*40];
};

template<bool SEM>
static __device__ __forceinline__ void attn_body(AttnSmem& sm,
    const short* __restrict__ WhT,
    const float* __restrict__ f1, const float* __restrict__ f2,
    const int* __restrict__ adjI, const float* __restrict__ vvec,
    const float* __restrict__ Svec,
    const short* __restrict__ resb,
    const float* __restrict__ g, const float* __restrict__ bt,
    short* __restrict__ bfout, int bf_ld, int bf_off, int bfpad){
  int b = blockIdx.x, i0 = blockIdx.y*64, tid = threadIdx.x;
  int lane = tid&63, wave = tid>>6;
  int lo = lane&31, hi = lane>>5;
  int rgrp = wave&1, cgrp = wave>>1;

  sm.s_f2[tid] = f2[b*NN+tid];
  float S = 0.f;
  if(SEM){ sm.s_v[tid] = vvec[b*NN+tid]; S = Svec[b]; }
  __syncthreads();

  {
    int r = tid>>2, q = tid&3, i = i0 + r;
    float fi = f1[b*NN+i];
    float vi = 0.f, denom = 0.f;
    if(SEM){ vi = sm.s_v[i]; denom = 0.5f*((float)NN*vi + S) + 1.f + 1e-8f; }
    const int* arow = (!SEM) ? (adjI + ((size_t)b*NN+i)*NN + q*64) : (const int*)0;
    float s = 0.f;
    #pragma unroll
    for(int c=0;c<8;c++){
      int jb = q*64 + c*8;
      int4 a0, a1_;
      if(!SEM){ a0 = *(const int4*)(arow + c*8); a1_ = *(const int4*)(arow + c*8 + 4); }
      short8 ps;
      #pragma unroll
      for(int k=0;k<8;k++){
        int j = jb + k;
        float ee = fi + sm.s_f2[j];
        ee = ee>0.f ? ee : 0.2f*ee;
        bool m;
        if(SEM){
          float val = 0.5f*(vi + sm.s_v[j]) + (i==j ? 1.f : 0.f);
          m = (denom > 0.f) ? (val > 0.f) : (val < 0.f);
        } else {
          m = ((k<4) ? (&a0.x)[k] : (&a1_.x)[k-4]) > 0;
        }
        float pv = m ? __expf(ee) : 0.f;
        s += pv;
        ps[k] = f2bf(pv);
      }
      *(short8*)&sm.sP[r][jb] = ps;
    }
    s += __shfl_xor(s,1,64);
    s += __shfl_xor(s,2,64);
    if(q==0) sm.s_inv[r] = 1.f/s;
  }
  __syncthreads();

  f32x16 acc[5];
  #pragma unroll
  for(int t=0;t<5;t++)
    #pragma unroll
    for(int i=0;i<16;i++) acc[t][i] = 0.f;

  const short* wtb = WhT + (size_t)b*320*256;
  for(int k0=0; k0<256; k0+=32){
    #pragma unroll
    for(int u=0;u<5;u++){
      int c = tid + u*256; int r=c>>2, cc=c&3;
      *(short8*)(sm.sB + r*40 + cc*8) = *(const short8*)(wtb + (size_t)r*256 + k0 + cc*8);
    }
    __syncthreads();
    #pragma unroll
    for(int ss=0; ss<2; ss++){
      short8 a = *(const short8*)&sm.sP[rgrp*32 + lo][k0 + ss*16 + hi*8];
      #pragma unroll
      for(int t=0;t<5;t++){
        short8 bb = *(const short8*)(sm.sB + (cgrp*160 + t*32 + lo)*40 + ss*16 + hi*8);
        acc[t] = __builtin_amdgcn_mfma_f32_32x32x16_bf16(a, bb, acc[t], 0, 0, 0);
      }
    }
    __syncthreads();
  }

  #pragma unroll
  for(int r=0;r<16;r++){
    int lr = rgrp*32 + (r&3) + 8*(r>>2) + 4*hi;
    float inv_s = sm.s_inv[lr];
    size_t grow = (size_t)(b*NN + i0 + lr);
    float sum = 0.f;
    #pragma unroll
    for(int t=0;t<5;t++){
      int nc = cgrp*160 + t*32 + lo;
      float x = 0.f;
      if(nc < GG){
        float rv = bf2f(resb[grow*320 + nc]);
        x = acc[t][r]*inv_s + rv;
      }
      acc[t][r] = x; sum += x;
    }
    for(int o=1;o<32;o<<=1) sum += __shfl_xor(sum,o,64);
    if(lo==0) sm.sRed[lr][cgrp] = sum;
  }
  __syncthreads();
  float mean[16];
  #pragma unroll
  for(int r=0;r<16;r++){
    int lr = rgrp*32 + (r&3) + 8*(r>>2) + 4*hi;
    mean[r] = (sm.sRed[lr][0] + sm.sRed[lr][1]) * (1.f/(float)GG);
  }
  __syncthreads();
  #pragma unroll
  for(int r=0;r<16;r++){
    int lr = rgrp*32 + (r&3) + 8*(r>>2) + 4*hi;
    float s = 0.f;
    #pragma unroll
    for(int t=0;t<5;t++){
      int nc = cgrp*160 + t*32 + lo;
      if(nc < GG){ float d = acc[t][r] - mean[r]; s += d*d; }
    }
    for(int o=1;o<32;o<<=1) s += __shfl_xor(s,o,64);
    if(lo==0) sm.sRed[lr][cgrp] = s;
  }
  __syncthreads();
  #pragma unroll
  for(int r=0;r<16;r++){
    int lr = rgrp*32 + (r&3) + 8*(r>>2) + 4*hi;
    size_t grow = (size_t)(b*NN + i0 + lr);
    float iv = 1.0f/sqrtf((sm.sRed[lr][0]+sm.sRed[lr][1])/(float)GG + 1e-5f);
    float mn = mean[r];
    #pragma unroll
    for(int t=0;t<5;t++){
      int nc = cgrp*160 + t*32 + lo;
      if(nc < GG){
        float y = fmaxf((acc[t][r]-mn)*iv*g[nc] + bt[nc], 0.f);
        bfout[grow*bf_ld + bf_off + nc] = f2bf(y);
      } else if(nc < bfpad){
        bfout[grow*bf_ld + bf_off + nc] = 0;
      }
    }
  }
}

__global__ __launch_bounds__(256) void k_attn2(
    const short* __restrict__ WhTA, const short* __restrict__ WhTB,
    const float* __restrict__ f1a, const float* __restrict__ f2a,
    const float* __restrict__ f1b, const float* __restrict__ f2b,
    const int* __restrict__ adjI, const float* __restrict__ vvec,
    const float* __restrict__ Svec,
    const short* __restrict__ resbA, const short* __restrict__ resbB,
    const float* __restrict__ gA, const float* __restrict__ btA,
    const float* __restrict__ gB, const float* __restrict__ btB,
    short* __restrict__ outA, int ldA, int offA, int padA,
    short* __restrict__ outB, int ldB, int offB, int padB){
  __shared__ AttnSmem sm;
  if(blockIdx.z==0)
    attn_body<false>(sm, WhTA, f1a, f2a, adjI, nullptr, nullptr, resbA, gA, btA, outA, ldA, offA, padA);
  else
    attn_body<true >(sm, WhTB, f1b, f2b, nullptr, vvec, Svec, resbB, gB, btB, outB, ldB, offB, padB);
}

// ---------------------------------------------------------------------------
extern "C" void kernel_launch(void* const* d_in, const int* in_sizes, int n_in,
                              void* d_out, int out_size, void* d_ws, size_t ws_size,
                              hipStream_t stream){
  const float* h     = (const float*)d_in[0];
  const float* amask = (const float*)d_in[1];
  const float *syn0_W=(const float*)d_in[2], *syn0_a1=(const float*)d_in[3], *syn0_a2=(const float*)d_in[4],
              *syn0_pos=(const float*)d_in[5], *syn0_tW=(const float*)d_in[6], *syn0_tb=(const float*)d_in[7],
              *syn0_g=(const float*)d_in[8], *syn0_b=(const float*)d_in[9];
  const float *syn1_W=(const float*)d_in[10], *syn1_a1=(const float*)d_in[11], *syn1_a2=(const float*)d_in[12],
              *syn1_pos=(const float*)d_in[13], *syn1_g=(const float*)d_in[14], *syn1_b=(const float*)d_in[15];
  const float *sem0_W=(const float*)d_in[16], *sem0_a1=(const float*)d_in[17], *sem0_a2=(const float*)d_in[18],
              *sem0_pos=(const float*)d_in[19], *sem0_tW=(const float*)d_in[20], *sem0_tb=(const float*)d_in[21],
              *sem0_g=(const float*)d_in[22], *sem0_b=(const float*)d_in[23];
  const float *sem1_W=(const float*)d_in[24], *sem1_a1=(const float*)d_in[25], *sem1_a2=(const float*)d_in[26],
              *sem1_pos=(const float*)d_in[27], *sem1_g=(const float*)d_in[28], *sem1_b=(const float*)d_in[29];
  const float *fus_W=(const float*)d_in[30], *fus_b=(const float*)d_in[31];
  const int* synadj    = (const int*)d_in[32];
  const int* positions = (const int*)d_in[33];
  float* out = (float*)d_out;

  // Workspace layout (total ~87.2 MB, below the proven-safe ~102.6 MB):
  // Xf ALIASES T1_syn/T1_sem (T1 dead after layer-0 attn; Xf born at layer-1 attn).
  float* ws   = (float*)d_ws;
  float* vvec = ws;                    // 16384
  float* Svec = vvec + 16384;          // 64
  float* f1a  = Svec + 64;             // 16384
  float* f2a  = f1a + 16384;           // 16384
  float* f1b  = f2a + 16384;           // 16384
  float* f2b  = f1b + 16384;           // 16384
  float* arep = f2b + 16384;           // 49152
  float* simb = arep + 49152;          // 16384  (147,520 floats total, 16B-aligned end)
  short* T1_syn  = (short*)(simb + 16384);      // [16384][320] bf16
  short* T1_sem  = T1_syn + 5242880;
  short* Xf      = T1_syn;                      // ALIAS: [16384][608] <= T1_syn+T1_sem
  short* Whb_syn = T1_sem + 5242880;            // [16384][320]
  short* Whb_sem = Whb_syn + 5242880;
  short* Xb_syn  = Whb_sem + 5242880;           // [16384][320]
  short* Xb_sem  = Xb_syn + 5242880;
  short* WhT_syn = Xb_sem + 5242880;            // [64][320][256]
  short* WhT_sem = WhT_syn + 5242880;
  short* Wt_all  = WhT_sem + 5242880;           // [1280][768]
  short* Wt_syn1 = Wt_all + 983040;             // [320][320]
  short* Wt_sem1 = Wt_syn1 + 102400;
  short* Wt_fus  = Wt_sem1 + 102400;            // [320][608]

  // semantic prep
  k_arep<<<dim3(BB,3),256,0,stream>>>(h, amask, arep);
  k_sim <<<dim3(BB,64),256,0,stream>>>(h, arep, simb);
  k_topk<<<BB,256,0,stream>>>(simb, vvec, Svec);

  // weight packs
  k_wcast4<<<3840,256,0,stream>>>(syn0_W, syn0_tW, sem0_W, sem0_tW, Wt_all);
  k_wcast<<<400,256,0,stream>>>(syn1_W, Wt_syn1, 300, 320, 320);
  k_wcast<<<400,256,0,stream>>>(sem1_W, Wt_sem1, 300, 320, 320);
  k_wcast<<<760,256,0,stream>>>(fus_W,  Wt_fus,  600, 608, 320);

  // merged layer-0 GEMM: Wh (bf16) + residuals (bf16) + folded f1/f2 per channel
  k_gemm<768,3,float><<<dim3(256,4,1),256,0,stream>>>(h, Wt_all, nullptr, nullptr,
      positions, syn0_pos, sem0_pos, syn0_tb, sem0_tb,
      syn0_a1, syn0_a2, sem0_a1, sem0_a2,
      Whb_syn, Whb_sem, T1_syn, T1_sem,
      f1a, f2a, f1b, f2b, nullptr);

  // ---- layer 0: both channels, z-merged ----
  k_whT<<<dim3(BB,4,2),256,0,stream>>>(Whb_syn, Whb_sem, WhT_syn, WhT_sem);
  k_attn2<<<dim3(BB,4,2),256,0,stream>>>(WhT_syn, WhT_sem, f1a, f2a, f1b, f2b,
      synadj, vvec, Svec, T1_syn, T1_sem,
      syn0_g, syn0_b, sem0_g, sem0_b,
      Xb_syn, 320, 0, 320, Xb_sem, 320, 0, 320);

  // ---- layer 1 GEMM: both channels, z-merged ----
  k_gemm<320,0,short><<<dim3(256,1,2),256,0,stream>>>(Xb_syn, Wt_syn1, Xb_sem, Wt_sem1,
      positions, syn1_pos, sem1_pos, nullptr, nullptr,
      syn1_a1, syn1_a2, sem1_a1, sem1_a2,
      Whb_syn, Whb_sem, nullptr, nullptr,
      f1a, f2a, f1b, f2b, nullptr);

  // ---- layer 1 attn: both channels, z-merged (T1 region now dead -> Xf) ----
  k_whT<<<dim3(BB,4,2),256,0,stream>>>(Whb_syn, Whb_sem, WhT_syn, WhT_sem);
  k_attn2<<<dim3(BB,4,2),256,0,stream>>>(WhT_syn, WhT_sem, f1a, f2a, f1b, f2b,
      synadj, vvec, Svec, Xb_syn, Xb_sem,
      syn1_g, syn1_b, sem1_g, sem1_b,
      Xf, 608, 0, 300, Xf, 608, 300, 308);

  // fusion: out = relu(concat @ fus_W + fus_b)
  k_gemm<608,2,short><<<dim3(256,1,1),256,0,stream>>>(Xf, Wt_fus, nullptr, nullptr,
      positions, nullptr, nullptr, fus_b, nullptr,
      nullptr, nullptr, nullptr, nullptr,
      nullptr, nullptr, nullptr, nullptr,
      nullptr, nullptr, nullptr, nullptr, out);
}

// Round 4
// 529.943 us; speedup vs baseline: 1.4119x; 1.0168x over previous
//
#include <hip/hip_runtime.h>
#include <hip/hip_bf16.h>
#include <math.h>

#define BB 64
#define NN 256
#define DD 768
#define GG 300
#define KK 10
#define NEGV -9e15f

typedef __attribute__((ext_vector_type(8)))  short short8;
typedef __attribute__((ext_vector_type(4)))  short short4v;
typedef __attribute__((ext_vector_type(16))) float f32x16;

static __device__ __forceinline__ short f2bf(float f){
  __hip_bfloat16 b = __float2bfloat16(f);
  return __builtin_bit_cast(short, b);
}
static __device__ __forceinline__ float bf2f(short s){
  return __bfloat162float(__builtin_bit_cast(__hip_bfloat16, s));
}

// async global->LDS DMA, 16B per lane; dst is wave-uniform base (+lane*16 by HW)
static __device__ __forceinline__ void dma16(const void* g, void* l){
  __builtin_amdgcn_global_load_lds((const __attribute__((address_space(1))) void*)g,
                                   (__attribute__((address_space(3))) void*)l, 16, 0, 0);
}

__device__ __forceinline__ float blkReduceSum(float v, float* s){
  for(int o=32;o>0;o>>=1) v += __shfl_down(v,o,64);
  int nw = blockDim.x>>6;
  __syncthreads();
  if((threadIdx.x&63)==0) s[threadIdx.x>>6]=v;
  __syncthreads();
  float r=s[0];
  for(int i=1;i<nw;i++) r+=s[i];
  return r;
}

// ---------------------------------------------------------------------------
// Semantic prep A: arep[b][d] = masked mean of h over nodes. grid (64,3).
// ---------------------------------------------------------------------------
__global__ __launch_bounds__(256) void k_arep(const float* __restrict__ h,
    const float* __restrict__ amask, float* __restrict__ arep){
  int b = blockIdx.x, tid = threadIdx.x;
  int d = blockIdx.y*256 + tid;
  __shared__ float s_mask[NN];
  __shared__ float s_red[4];
  s_mask[tid] = amask[b*NN+tid];
  float cnt = blkReduceSum(s_mask[tid], s_red);
  const float* hb = h + (size_t)b*NN*DD + d;
  float a = 0.f;
  #pragma unroll 8
  for(int n=0;n<NN;n++) a += hb[(size_t)n*DD] * s_mask[n];
  arep[b*DD + d] = a/(cnt+1e-8f);
}

// ---------------------------------------------------------------------------
// Semantic prep B: sim[b][n] = cos(h[b,n,:], arep[b,:]). grid (64,64).
// ROUND-12: also emits hb16 = bf16(h) (free: h is already fully read here).
// gemm0 consumes hb16 via the pure-DMA path -> halves X fetch, kills in-loop
// f32->bf16 VALU convert. Rounding identical to previous in-gemm convert.
// ---------------------------------------------------------------------------
__global__ __launch_bounds__(256) void k_sim(const float* __restrict__ h,
    const float* __restrict__ arep, float* __restrict__ sim,
    short* __restrict__ hb16){
  int b = blockIdx.x, tid = threadIdx.x;
  int lane = tid&63, w = tid>>6;
  __shared__ __align__(16) float s_a[DD];
  __shared__ float s_red[4];
  float pa = 0.f;
  for(int d=tid; d<DD; d+=256){ float v = arep[b*DD+d]; s_a[d]=v; pa += v*v; }
  float na = blkReduceSum(pa, s_red);
  float nac = fmaxf(sqrtf(na), 1e-12f);
  int node = blockIdx.y*4 + w;
  const float* hr = h + ((size_t)b*NN+node)*DD;
  short* hw = hb16 + ((size_t)b*NN+node)*DD;
  float dot=0.f, nn=0.f;
  #pragma unroll
  for(int q=0;q<3;q++){
    int c = lane*4 + q*256;
    float4 hv = *(const float4*)(hr + c);
    float4 av = *(const float4*)(s_a + c);
    dot += hv.x*av.x + hv.y*av.y + hv.z*av.z + hv.w*av.w;
    nn  += hv.x*hv.x + hv.y*hv.y + hv.z*hv.z + hv.w*hv.w;
    short4v sv; sv.x=f2bf(hv.x); sv.y=f2bf(hv.y); sv.z=f2bf(hv.z); sv.w=f2bf(hv.w);
    *(short4v*)(hw + c) = sv;
  }
  for(int o=32;o>0;o>>=1){ dot += __shfl_down(dot,o,64); nn += __shfl_down(nn,o,64); }
  if(lane==0){
    nn = fmaxf(sqrtf(nn), 1e-12f);
    sim[b*NN+node] = dot/(nn*nac);
  }
}

// ---------------------------------------------------------------------------
// Semantic prep C: stable top-K per batch -> scattered v[b,:], S[b].
// ---------------------------------------------------------------------------
__global__ __launch_bounds__(256) void k_topk(const float* __restrict__ sim,
    float* __restrict__ vout, float* __restrict__ Sout){
  int b = blockIdx.x, tid = threadIdx.x;
  __shared__ float s_bv[4]; __shared__ int s_bi[4];
  __shared__ float s_tv[KK]; __shared__ int s_ti[KK];
  __shared__ float s_v[NN];
  float v = sim[b*NN+tid];
  int lane = tid&63, w = tid>>6;
  for(int k=0;k<KK;k++){
    float bv = v; int bi_ = tid;
    for(int o=32;o>0;o>>=1){
      float ov = __shfl_down(bv,o,64); int oi = __shfl_down(bi_,o,64);
      if(ov>bv || (ov==bv && oi<bi_)){ bv=ov; bi_=oi; }
    }
    if(lane==0){ s_bv[w]=bv; s_bi[w]=bi_; }
    __syncthreads();
    float gb = s_bv[0]; int gi = s_bi[0];
    for(int i=1;i<4;i++){ if(s_bv[i]>gb || (s_bv[i]==gb && s_bi[i]<gi)){ gb=s_bv[i]; gi=s_bi[i]; } }
    if(tid==0){ s_tv[k]=gb; s_ti[k]=gi; }
    if(tid==gi) v = -1e30f;
    __syncthreads();
  }
  s_v[tid]=0.f;
  __syncthreads();
  if(tid<KK) s_v[s_ti[tid]] = s_tv[tid];
  __syncthreads();
  float S=0.f;
  for(int k=0;k<KK;k++) S += s_tv[k];
  vout[b*NN+tid] = s_v[tid];
  if(tid==0) Sout[b] = S;
}

// ---------------------------------------------------------------------------
// Weight cast+transpose+pad: dst[n][k] bf16 [NPAD][KPAD] from W[k][300].
// ---------------------------------------------------------------------------
__global__ __launch_bounds__(256) void k_wcast(const float* __restrict__ W1,
    short* __restrict__ dst, int K, int KPAD, int NPAD){
  int idx = blockIdx.x*256 + threadIdx.x;
  if(idx >= NPAD*KPAD) return;
  int n = idx / KPAD, k = idx % KPAD;
  float v = (k < K && n < 300) ? W1[(size_t)k*300 + n] : 0.f;
  dst[idx] = f2bf(v);
}

// Quad pack for merged layer-0 GEMM: dst [1280][768], 4 segments of 320 rows:
// {syn0_W, syn0_tW, sem0_W, sem0_tW}, each 300 used + 20 zero pad.
__global__ __launch_bounds__(256) void k_wcast4(const float* __restrict__ W0,
    const float* __restrict__ W1, const float* __restrict__ W2,
    const float* __restrict__ W3, short* __restrict__ dst){
  int idx = blockIdx.x*256 + threadIdx.x;
  if(idx >= 1280*768) return;
  int n = idx / 768, k = idx - (n*768);
  int seg = n/320; int nl = n - seg*320;
  const float* src = (seg==0)?W0 : (seg==1)?W1 : (seg==2)?W2 : W3;
  float v = (nl<300) ? src[(size_t)k*300 + nl] : 0.f;
  dst[idx] = f2bf(v);
}

// ---------------------------------------------------------------------------
// MFMA GEMM. Y = X[M][KPAD] @ Wt^T, Wt[NPAD][KPAD] bf16. BM=64, BN=320, BK=32.
// Single-buffer schedule (inter-block overlap), bank-conflict XOR key
// ((row>>1)&3) on both DMA-source granule and ds_read position.
// ROUND-12: all instantiations now XT=short (pure dma16 staging; gemm0 reads
// pre-cast hb16). sX shrinks to [64*32].
// ---------------------------------------------------------------------------
template<int KPAD, int MODE, typename XT>
__global__ __launch_bounds__(256,4) void k_gemm(const XT* __restrict__ X,
    const short* __restrict__ Bt,
    const XT* __restrict__ X2, const short* __restrict__ Bt2,
    const int* __restrict__ positions,
    const float* __restrict__ posA, const float* __restrict__ posB,
    const float* __restrict__ tbA, const float* __restrict__ tbB,
    const float* __restrict__ a1A, const float* __restrict__ a2A,
    const float* __restrict__ a1B, const float* __restrict__ a2B,
    short* __restrict__ whbA, short* __restrict__ whbB,
    short* __restrict__ t1A, short* __restrict__ t1B,
    float* __restrict__ f1A, float* __restrict__ f2A,
    float* __restrict__ f1B, float* __restrict__ f2B,
    float* __restrict__ outf){
  __shared__ __align__(16) short sX[sizeof(XT)==4 ? 64*40 : 64*32];
  __shared__ __align__(16) short sB[320*32];
  __shared__ float sF1[64][2], sF2[64][2];
  const int tid = threadIdx.x;
  const int lane = tid & 63, wave = tid >> 6;
  const int rgrp = wave & 1, cgrp = wave >> 1;
  const int row0 = blockIdx.x * 64;
  const int ncol0 = blockIdx.y * 320;
  const int lo = lane & 31, hi = lane >> 5;
  constexpr int NIT = KPAD/32;
  const int phase = (int)((blockIdx.x*7 + blockIdx.y*3) % NIT);
  const int drow = lane>>2;                        // 0..15
  const int dk   = ((lane&3) ^ ((drow>>1)&3))*8;   // swizzled k-granule (shorts)
  const int rk   = (lo>>1)&3;                      // read-side XOR key

  // channel selection for merged MODE 0 (blockIdx.z)
  const XT* Xp = X; const short* Btp = Bt;
  const float *posS=posA, *a1S=a1A, *a2S=a2A;
  short* whbS=whbA; float *f1S=f1A, *f2S=f2A;
  if constexpr (MODE==0){
    if(blockIdx.z==1){ Xp=X2; Btp=Bt2; posS=posB; a1S=a1B; a2S=a2B; whbS=whbB; f1S=f1B; f2S=f2B; }
  }

  f32x16 acc[5];
  #pragma unroll
  for(int t=0;t<5;t++)
    #pragma unroll
    for(int i=0;i<16;i++) acc[t][i] = 0.f;

  float4 rx0, rx1;
  if constexpr (sizeof(XT)==4){
    int k0 = phase*32;
    int c0=tid, c1=tid+256;
    rx0 = *(const float4*)(Xp + (size_t)(row0+(c0>>3))*KPAD + k0 + (c0&7)*4);
    rx1 = *(const float4*)(Xp + (size_t)(row0+(c1>>3))*KPAD + k0 + (c1&7)*4);
  }

  for(int it=0; it<NIT; it++){
    int kv = it + phase; if(kv >= NIT) kv -= NIT;
    int k0 = kv*32;
    if constexpr (sizeof(XT)==4){
      { int c=tid; short4v s; s.x=f2bf(rx0.x); s.y=f2bf(rx0.y); s.z=f2bf(rx0.z); s.w=f2bf(rx0.w);
        *(short4v*)(sX + (c>>3)*40 + (c&7)*4) = s; }
      { int c=tid+256; short4v s; s.x=f2bf(rx1.x); s.y=f2bf(rx1.y); s.z=f2bf(rx1.z); s.w=f2bf(rx1.w);
        *(short4v*)(sX + (c>>3)*40 + (c&7)*4) = s; }
    } else {
      dma16(Xp + (size_t)(row0 + wave*16 + drow)*KPAD + k0 + dk, sX + wave*512);
    }
    #pragma unroll
    for(int u=0;u<5;u++){
      int q = wave*5+u;
      dma16(Btp + (size_t)(ncol0 + q*16 + drow)*KPAD + k0 + dk, sB + q*512);
    }
    __syncthreads();
    if constexpr (sizeof(XT)==4){
      if(it+1 < NIT){
        int kn = it+1+phase; if(kn >= NIT) kn -= NIT;
        int k1 = kn*32;
        int c0=tid, c1=tid+256;
        rx0 = *(const float4*)(Xp + (size_t)(row0+(c0>>3))*KPAD + k1 + (c0&7)*4);
        rx1 = *(const float4*)(Xp + (size_t)(row0+(c1>>3))*KPAD + k1 + (c1&7)*4);
      }
    }
    #pragma unroll
    for(int ss=0; ss<2; ss++){
      short8 a;
      if constexpr (sizeof(XT)==4){
        a = *(const short8*)(sX + (rgrp*32 + lo)*40 + ss*16 + hi*8);
      } else {
        a = *(const short8*)(sX + (rgrp*32 + lo)*32 + (((ss*2+hi)^rk)*8));
      }
      #pragma unroll
      for(int t=0;t<5;t++){
        short8 b = *(const short8*)(sB + (cgrp*160 + t*32 + lo)*32 + (((ss*2+hi)^rk)*8));
        acc[t] = __builtin_amdgcn_mfma_f32_32x32x16_bf16(a, b, acc[t], 0, 0, 0);
      }
    }
    __syncthreads();
  }

  // ---- epilogue ----
  const int seg = (MODE==3) ? blockIdx.y : 0;
  const bool fold = (MODE==0) || (MODE==3 && (seg==0 || seg==2));
  float* sAv = (float*)sB;   // reuse LDS for a1/a2 cache (last barrier passed)
  if(fold){
    const float* a1v; const float* a2v;
    if constexpr (MODE==0){ a1v = a1S; a2v = a2S; }
    else { a1v = (seg==2) ? a1B : a1A; a2v = (seg==2) ? a2B : a2A; }
    for(int c=tid; c<300; c+=256){ sAv[c] = a1v[c]; sAv[c+300] = a2v[c]; }
    __syncthreads();
  }
  #pragma unroll
  for(int r=0;r<16;r++){
    int lr = rgrp*32 + (r&3) + 8*(r>>2) + 4*hi;
    int row = row0 + lr;
    int p = (MODE!=2) ? positions[row] : 0;
    float s1=0.f, s2=0.f;
    #pragma unroll
    for(int t=0;t<5;t++){
      int nc = cgrp*160 + t*32 + lo;
      float v = acc[t][r];
      if(nc < 300){
        if(MODE==2){
          outf[(size_t)row*300 + nc] = fmaxf(v + tbA[nc], 0.f);
        } else if(MODE==0){
          float y = v + posS[(size_t)p*300 + nc];
          whbS[(size_t)row*320 + nc] = f2bf(y);
          s1 += y*sAv[nc]; s2 += y*sAv[300+nc];
        } else { // MODE 3
          if(seg==0){
            float y = v + posA[(size_t)p*300 + nc];
            whbA[(size_t)row*320 + nc] = f2bf(y);
            s1 += y*sAv[nc]; s2 += y*sAv[300+nc];
          } else if(seg==1){
            t1A[(size_t)row*320 + nc] = f2bf(v + tbA[nc]);
          } else if(seg==2){
            float y = v + posB[(size_t)p*300 + nc];
            whbB[(size_t)row*320 + nc] = f2bf(y);
            s1 += y*sAv[nc]; s2 += y*sAv[300+nc];
          } else {
            t1B[(size_t)row*320 + nc] = f2bf(v + tbB[nc]);
          }
        }
      }
    }
    if(fold){
      for(int o=1;o<32;o<<=1){ s1 += __shfl_xor(s1,o,64); s2 += __shfl_xor(s2,o,64); }
      if(lo==0){ sF1[lr][cgrp] = s1; sF2[lr][cgrp] = s2; }
    }
  }
  if(fold){
    __syncthreads();
    if(tid < 64){
      float* f1o; float* f2o;
      if constexpr (MODE==0){ f1o = f1S; f2o = f2S; }
      else { f1o = (seg==2) ? f1B : f1A; f2o = (seg==2) ? f2B : f2A; }
      f1o[row0+tid] = sF1[tid][0] + sF1[tid][1];
      f2o[row0+tid] = sF2[tid][0] + sF2[tid][1];
    }
  }
}

// ---------------------------------------------------------------------------
// Pure Wh transpose, z-merged over channels: grid (64,4,2).
// ---------------------------------------------------------------------------
__global__ __launch_bounds__(256) void k_whT(const short* __restrict__ WhbA,
    const short* __restrict__ WhbB, short* __restrict__ WhTA,
    short* __restrict__ WhTB){
  const short* Whb = blockIdx.z ? WhbB : WhbA;
  short* WhT = blockIdx.z ? WhTB : WhTA;
  __shared__ short s_t[64][308];
  int b = blockIdx.x, j0 = blockIdx.y*64, tid = threadIdx.x;
  for(int c=tid; c<64*300; c+=256){
    int r = c/300, n = c - r*300;
    s_t[r][n] = Whb[((size_t)(b*NN + j0 + r))*320 + n];
  }
  __syncthreads();
  for(int c=tid; c<320*64; c+=256){
    int n = c>>6, jj = c&63;
    WhT[((size_t)b*320 + n)*256 + j0 + jj] = (n<GG) ? s_t[jj][n] : (short)0;
  }
}

// ---------------------------------------------------------------------------
// Fused attention (MFMA) + residual(bf16) + LayerNorm + ReLU.
// z-merged over channels: grid (64,4,2); z=0 syn (adj mask), z=1 sem.
// LDS ~62KB (single-buffer sB) so 2 blocks/CU fit.
// ---------------------------------------------------------------------------
struct AttnSmem {
  float s_f2[NN];
  float s_v[NN];
  float s_inv[64];
  float sRed[64][2];
  alignas(16) short sP[64][264];
  alignas(16) short sB[320*40];
};

template<bool SEM>
static __device__ __forceinline__ void attn_body(AttnSmem& sm,
    const short* __restrict__ WhT,
    const float* __restrict__ f1, const float* __restrict__ f2,
    const int* __restrict__ adjI, const float* __restrict__ vvec,
    const float* __restrict__ Svec,
    const short* __restrict__ resb,
    const float* __restrict__ g, const float* __restrict__ bt,
    short* __restrict__ bfout, int bf_ld, int bf_off, int bfpad){
  int b = blockIdx.x, i0 = blockIdx.y*64, tid = threadIdx.x;
  int lane = tid&63, wave = tid>>6;
  int lo = lane&31, hi = lane>>5;
  int rgrp = wave&1, cgrp = wave>>1;

  sm.s_f2[tid] = f2[b*NN+tid];
  float S = 0.f;
  if(SEM){ sm.s_v[tid] = vvec[b*NN+tid]; S = Svec[b]; }
  __syncthreads();

  {
    int r = tid>>2, q = tid&3, i = i0 + r;
    float fi = f1[b*NN+i];
    float vi = 0.f, denom = 0.f;
    if(SEM){ vi = sm.s_v[i]; denom = 0.5f*((float)NN*vi + S) + 1.f + 1e-8f; }
    const int* arow = (!SEM) ? (adjI + ((size_t)b*NN+i)*NN + q*64) : (const int*)0;
    float s = 0.f;
    #pragma unroll
    for(int c=0;c<8;c++){
      int jb = q*64 + c*8;
      int4 a0, a1_;
      if(!SEM){ a0 = *(const int4*)(arow + c*8); a1_ = *(const int4*)(arow + c*8 + 4); }
      short8 ps;
      #pragma unroll
      for(int k=0;k<8;k++){
        int j = jb + k;
        float ee = fi + sm.s_f2[j];
        ee = ee>0.f ? ee : 0.2f*ee;
        bool m;
        if(SEM){
          float val = 0.5f*(vi + sm.s_v[j]) + (i==j ? 1.f : 0.f);
          m = (denom > 0.f) ? (val > 0.f) : (val < 0.f);
        } else {
          m = ((k<4) ? (&a0.x)[k] : (&a1_.x)[k-4]) > 0;
        }
        float pv = m ? __expf(ee) : 0.f;
        s += pv;
        ps[k] = f2bf(pv);
      }
      *(short8*)&sm.sP[r][jb] = ps;
    }
    s += __shfl_xor(s,1,64);
    s += __shfl_xor(s,2,64);
    if(q==0) sm.s_inv[r] = 1.f/s;
  }
  __syncthreads();

  f32x16 acc[5];
  #pragma unroll
  for(int t=0;t<5;t++)
    #pragma unroll
    for(int i=0;i<16;i++) acc[t][i] = 0.f;

  const short* wtb = WhT + (size_t)b*320*256;
  for(int k0=0; k0<256; k0+=32){
    #pragma unroll
    for(int u=0;u<5;u++){
      int c = tid + u*256; int r=c>>2, cc=c&3;
      *(short8*)(sm.sB + r*40 + cc*8) = *(const short8*)(wtb + (size_t)r*256 + k0 + cc*8);
    }
    __syncthreads();
    #pragma unroll
    for(int ss=0; ss<2; ss++){
      short8 a = *(const short8*)&sm.sP[rgrp*32 + lo][k0 + ss*16 + hi*8];
      #pragma unroll
      for(int t=0;t<5;t++){
        short8 bb = *(const short8*)(sm.sB + (cgrp*160 + t*32 + lo)*40 + ss*16 + hi*8);
        acc[t] = __builtin_amdgcn_mfma_f32_32x32x16_bf16(a, bb, acc[t], 0, 0, 0);
      }
    }
    __syncthreads();
  }

  #pragma unroll
  for(int r=0;r<16;r++){
    int lr = rgrp*32 + (r&3) + 8*(r>>2) + 4*hi;
    float inv_s = sm.s_inv[lr];
    size_t grow = (size_t)(b*NN + i0 + lr);
    float sum = 0.f;
    #pragma unroll
    for(int t=0;t<5;t++){
      int nc = cgrp*160 + t*32 + lo;
      float x = 0.f;
      if(nc < GG){
        float rv = bf2f(resb[grow*320 + nc]);
        x = acc[t][r]*inv_s + rv;
      }
      acc[t][r] = x; sum += x;
    }
    for(int o=1;o<32;o<<=1) sum += __shfl_xor(sum,o,64);
    if(lo==0) sm.sRed[lr][cgrp] = sum;
  }
  __syncthreads();
  float mean[16];
  #pragma unroll
  for(int r=0;r<16;r++){
    int lr = rgrp*32 + (r&3) + 8*(r>>2) + 4*hi;
    mean[r] = (sm.sRed[lr][0] + sm.sRed[lr][1]) * (1.f/(float)GG);
  }
  __syncthreads();
  #pragma unroll
  for(int r=0;r<16;r++){
    int lr = rgrp*32 + (r&3) + 8*(r>>2) + 4*hi;
    float s = 0.f;
    #pragma unroll
    for(int t=0;t<5;t++){
      int nc = cgrp*160 + t*32 + lo;
      if(nc < GG){ float d = acc[t][r] - mean[r]; s += d*d; }
    }
    for(int o=1;o<32;o<<=1) s += __shfl_xor(s,o,64);
    if(lo==0) sm.sRed[lr][cgrp] = s;
  }
  __syncthreads();
  #pragma unroll
  for(int r=0;r<16;r++){
    int lr = rgrp*32 + (r&3) + 8*(r>>2) + 4*hi;
    size_t grow = (size_t)(b*NN + i0 + lr);
    float iv = 1.0f/sqrtf((sm.sRed[lr][0]+sm.sRed[lr][1])/(float)GG + 1e-5f);
    float mn = mean[r];
    #pragma unroll
    for(int t=0;t<5;t++){
      int nc = cgrp*160 + t*32 + lo;
      if(nc < GG){
        float y = fmaxf((acc[t][r]-mn)*iv*g[nc] + bt[nc], 0.f);
        bfout[grow*bf_ld + bf_off + nc] = f2bf(y);
      } else if(nc < bfpad){
        bfout[grow*bf_ld + bf_off + nc] = 0;
      }
    }
  }
}

__global__ __launch_bounds__(256) void k_attn2(
    const short* __restrict__ WhTA, const short* __restrict__ WhTB,
    const float* __restrict__ f1a, const float* __restrict__ f2a,
    const float* __restrict__ f1b, const float* __restrict__ f2b,
    const int* __restrict__ adjI, const float* __restrict__ vvec,
    const float* __restrict__ Svec,
    const short* __restrict__ resbA, const short* __restrict__ resbB,
    const float* __restrict__ gA, const float* __restrict__ btA,
    const float* __restrict__ gB, const float* __restrict__ btB,
    short* __restrict__ outA, int ldA, int offA, int padA,
    short* __restrict__ outB, int ldB, int offB, int padB){
  __shared__ AttnSmem sm;
  if(blockIdx.z==0)
    attn_body<false>(sm, WhTA, f1a, f2a, adjI, nullptr, nullptr, resbA, gA, btA, outA, ldA, offA, padA);
  else
    attn_body<true >(sm, WhTB, f1b, f2b, nullptr, vvec, Svec, resbB, gB, btB, outB, ldB, offB, padB);
}

// ---------------------------------------------------------------------------
extern "C" void kernel_launch(void* const* d_in, const int* in_sizes, int n_in,
                              void* d_out, int out_size, void* d_ws, size_t ws_size,
                              hipStream_t stream){
  const float* h     = (const float*)d_in[0];
  const float* amask = (const float*)d_in[1];
  const float *syn0_W=(const float*)d_in[2], *syn0_a1=(const float*)d_in[3], *syn0_a2=(const float*)d_in[4],
              *syn0_pos=(const float*)d_in[5], *syn0_tW=(const float*)d_in[6], *syn0_tb=(const float*)d_in[7],
              *syn0_g=(const float*)d_in[8], *syn0_b=(const float*)d_in[9];
  const float *syn1_W=(const float*)d_in[10], *syn1_a1=(const float*)d_in[11], *syn1_a2=(const float*)d_in[12],
              *syn1_pos=(const float*)d_in[13], *syn1_g=(const float*)d_in[14], *syn1_b=(const float*)d_in[15];
  const float *sem0_W=(const float*)d_in[16], *sem0_a1=(const float*)d_in[17], *sem0_a2=(const float*)d_in[18],
              *sem0_pos=(const float*)d_in[19], *sem0_tW=(const float*)d_in[20], *sem0_tb=(const float*)d_in[21],
              *sem0_g=(const float*)d_in[22], *sem0_b=(const float*)d_in[23];
  const float *sem1_W=(const float*)d_in[24], *sem1_a1=(const float*)d_in[25], *sem1_a2=(const float*)d_in[26],
              *sem1_pos=(const float*)d_in[27], *sem1_g=(const float*)d_in[28], *sem1_b=(const float*)d_in[29];
  const float *fus_W=(const float*)d_in[30], *fus_b=(const float*)d_in[31];
  const int* synadj    = (const int*)d_in[32];
  const int* positions = (const int*)d_in[33];
  float* out = (float*)d_out;

  // Workspace layout (total ~87.2 MB).
  // Aliases: Xf = T1_syn (T1 dead after layer-0 attn; Xf born at layer-1 attn).
  //          hb16 = WhT_syn (spans WhT_syn+WhT_sem+head of Xb_syn; hb16 live
  //          k_sim -> gemm0, all overlapped buffers first written after gemm0).
  float* ws   = (float*)d_ws;
  float* vvec = ws;                    // 16384
  float* Svec = vvec + 16384;          // 64
  float* f1a  = Svec + 64;             // 16384
  float* f2a  = f1a + 16384;           // 16384
  float* f1b  = f2a + 16384;           // 16384
  float* f2b  = f1b + 16384;           // 16384
  float* arep = f2b + 16384;           // 49152
  float* simb = arep + 49152;          // 16384  (147,520 floats, 16B-aligned end)
  short* T1_syn  = (short*)(simb + 16384);      // [16384][320] bf16
  short* T1_sem  = T1_syn + 5242880;
  short* Xf      = T1_syn;                      // ALIAS: [16384][608] <= T1 pair
  short* Whb_syn = T1_sem + 5242880;            // [16384][320]
  short* Whb_sem = Whb_syn + 5242880;
  short* WhT_syn = Whb_sem + 5242880;           // [64][320][256]
  short* WhT_sem = WhT_syn + 5242880;
  short* Xb_syn  = WhT_sem + 5242880;           // [16384][320]
  short* Xb_sem  = Xb_syn + 5242880;
  short* hb16    = WhT_syn;                     // ALIAS: [16384][768] bf16 (12.58M)
  short* Wt_all  = Xb_sem + 5242880;            // [1280][768]
  short* Wt_syn1 = Wt_all + 983040;             // [320][320]
  short* Wt_sem1 = Wt_syn1 + 102400;
  short* Wt_fus  = Wt_sem1 + 102400;            // [320][608]

  // semantic prep (+ hb16 emit inside k_sim)
  k_arep<<<dim3(BB,3),256,0,stream>>>(h, amask, arep);
  k_sim <<<dim3(BB,64),256,0,stream>>>(h, arep, simb, hb16);
  k_topk<<<BB,256,0,stream>>>(simb, vvec, Svec);

  // weight packs
  k_wcast4<<<3840,256,0,stream>>>(syn0_W, syn0_tW, sem0_W, sem0_tW, Wt_all);
  k_wcast<<<400,256,0,stream>>>(syn1_W, Wt_syn1, 300, 320, 320);
  k_wcast<<<400,256,0,stream>>>(sem1_W, Wt_sem1, 300, 320, 320);
  k_wcast<<<760,256,0,stream>>>(fus_W,  Wt_fus,  600, 608, 320);

  // merged layer-0 GEMM (bf16 X via hb16, pure-DMA staging)
  k_gemm<768,3,short><<<dim3(256,4,1),256,0,stream>>>(hb16, Wt_all, nullptr, nullptr,
      positions, syn0_pos, sem0_pos, syn0_tb, sem0_tb,
      syn0_a1, syn0_a2, sem0_a1, sem0_a2,
      Whb_syn, Whb_sem, T1_syn, T1_sem,
      f1a, f2a, f1b, f2b, nullptr);

  // ---- layer 0: both channels, z-merged (hb16 dead from here on) ----
  k_whT<<<dim3(BB,4,2),256,0,stream>>>(Whb_syn, Whb_sem, WhT_syn, WhT_sem);
  k_attn2<<<dim3(BB,4,2),256,0,stream>>>(WhT_syn, WhT_sem, f1a, f2a, f1b, f2b,
      synadj, vvec, Svec, T1_syn, T1_sem,
      syn0_g, syn0_b, sem0_g, sem0_b,
      Xb_syn, 320, 0, 320, Xb_sem, 320, 0, 320);

  // ---- layer 1 GEMM: both channels, z-merged ----
  k_gemm<320,0,short><<<dim3(256,1,2),256,0,stream>>>(Xb_syn, Wt_syn1, Xb_sem, Wt_sem1,
      positions, syn1_pos, sem1_pos, nullptr, nullptr,
      syn1_a1, syn1_a2, sem1_a1, sem1_a2,
      Whb_syn, Whb_sem, nullptr, nullptr,
      f1a, f2a, f1b, f2b, nullptr);

  // ---- layer 1 attn: both channels, z-merged (T1 region now dead -> Xf) ----
  k_whT<<<dim3(BB,4,2),256,0,stream>>>(Whb_syn, Whb_sem, WhT_syn, WhT_sem);
  k_attn2<<<dim3(BB,4,2),256,0,stream>>>(WhT_syn, WhT_sem, f1a, f2a, f1b, f2b,
      synadj, vvec, Svec, Xb_syn, Xb_sem,
      syn1_g, syn1_b, sem1_g, sem1_b,
      Xf, 608, 0, 300, Xf, 608, 300, 308);

  // fusion: out = relu(concat @ fus_W + fus_b)
  k_gemm<608,2,short><<<dim3(256,1,1),256,0,stream>>>(Xf, Wt_fus, nullptr, nullptr,
      positions, nullptr, nullptr, fus_b, nullptr,
      nullptr, nullptr, nullptr, nullptr,
      nullptr, nullptr, nullptr, nullptr,
      nullptr, nullptr, nullptr, nullptr, out);
}